// Round 1
// baseline (8146.021 us; speedup 1.0000x reference)
//
#include <hip/hip_runtime.h>
#include <hip/hip_bf16.h>
#include <stdint.h>

#define B_SZ 8192
#define T_SZ 24
#define H_SZ 1024
#define G4   4096   // 4*H

typedef __attribute__((ext_vector_type(8))) short bf16x8;
typedef __attribute__((ext_vector_type(4))) float f32x4;

// ---------------- prep kernels ----------------
__global__ void k_cvt_bf16(const float* __restrict__ src, __hip_bfloat16* __restrict__ dst, int n) {
    int i = blockIdx.x * blockDim.x + threadIdx.x;
    if (i < n) dst[i] = __float2bfloat16(src[i]);
}

// Wcat[n][k] = k<1024 ? W_ih2[n][k] : W_hh2[n][k-1024]   (row-major [4096][2048], bf16)
__global__ void k_build_wcat(const float* __restrict__ Wih2, const float* __restrict__ Whh2,
                             __hip_bfloat16* __restrict__ dst) {
    int i = blockIdx.x * blockDim.x + threadIdx.x;   // over 4096*2048
    int n = i >> 11, k = i & 2047;
    float v = (k < 1024) ? Wih2[n * 1024 + k] : Whh2[n * 1024 + (k - 1024)];
    dst[i] = __float2bfloat16(v);
}

__global__ void k_bias(const float* __restrict__ a1, const float* __restrict__ b1,
                       const float* __restrict__ a2, const float* __restrict__ b2,
                       float* __restrict__ o1, float* __restrict__ o2) {
    int i = blockIdx.x * blockDim.x + threadIdx.x;
    if (i < G4) { o1[i] = a1[i] + b1[i]; o2[i] = a2[i] + b2[i]; }
}

// c1,c2 fp32 masters; h1,h2 -> bf16 into concatenated A2 [B][2048] = [h1 | h2]
__global__ void k_init_state(const float* __restrict__ h1_0, const float* __restrict__ c1_0,
                             const float* __restrict__ h2_0, const float* __restrict__ c2_0,
                             __hip_bfloat16* __restrict__ A2, float* __restrict__ c1,
                             float* __restrict__ c2) {
    int i = blockIdx.x * blockDim.x + threadIdx.x;   // over B*H
    if (i >= B_SZ * H_SZ) return;
    int b = i >> 10, j = i & 1023;
    A2[(size_t)b * 2048 + j]        = __float2bfloat16(h1_0[i]);
    A2[(size_t)b * 2048 + 1024 + j] = __float2bfloat16(h2_0[i]);
    c1[i] = c1_0[i];
    c2[i] = c2_0[i];
}

// ---------------- GEMM: C[M,N] = A[M,K] * B[N,K]^T  (bf16 in, fp32 out) ----------------
// m97 structure: 128x128 tile, BK=64, 4 waves (2x2), 16x16x32 MFMA, global_load_lds w=16,
// XOR-swizzled global source (chunk ^= row&7) so linear LDS dest reads conflict-free.
#define BM 128
#define BN 128
#define BK 64

__global__ __launch_bounds__(256)
void k_gemm_bt(const __hip_bfloat16* __restrict__ A, int lda,
               const __hip_bfloat16* __restrict__ Bw, int ldb,
               float* __restrict__ C, int ldc, int K) {
    __shared__ short As[BM][BK];
    __shared__ short Bs[BN][BK];
    const int tid  = threadIdx.x;
    const int lane = tid & 63;
    const int wid  = tid >> 6;
    const int m0 = blockIdx.y * BM;
    const int n0 = blockIdx.x * BN;
    const int wm = wid >> 1, wn = wid & 1;
    const int fr = lane & 15;   // fragment row/col
    const int kg = lane >> 4;   // k-group 0..3

    f32x4 acc[4][4];
#pragma unroll
    for (int i = 0; i < 4; ++i)
#pragma unroll
        for (int j = 0; j < 4; ++j) acc[i][j] = (f32x4)0.f;

    for (int kt = 0; kt < K; kt += BK) {
        // stage A and B tiles: 1024 chunks of 16B each per tile
#pragma unroll
        for (int it = 0; it < 4; ++it) {
            int cbase = it * 256 + wid * 64;       // wave-uniform chunk base
            int ci  = cbase + lane;
            int row = ci >> 3, cr = ci & 7;
            int scol = ((cr ^ (row & 7)) << 3);    // pre-swizzled source column (elems)
            const __hip_bfloat16* ga = A  + (size_t)(m0 + row) * lda + kt + scol;
            const __hip_bfloat16* gb = Bw + (size_t)(n0 + row) * ldb + kt + scol;
            __builtin_amdgcn_global_load_lds(
                (const __attribute__((address_space(1))) void*)ga,
                (__attribute__((address_space(3))) void*)(&As[0][0] + (size_t)cbase * 8),
                16, 0, 0);
            __builtin_amdgcn_global_load_lds(
                (const __attribute__((address_space(1))) void*)gb,
                (__attribute__((address_space(3))) void*)(&Bs[0][0] + (size_t)cbase * 8),
                16, 0, 0);
        }
        __syncthreads();   // compiler drains vmcnt before s_barrier

#pragma unroll
        for (int ks = 0; ks < 2; ++ks) {
            bf16x8 af[4], bfr[4];
#pragma unroll
            for (int m = 0; m < 4; ++m) {
                int row = wm * 64 + m * 16 + fr;
                int chunk = (ks * 4 + kg) ^ (row & 7);
                af[m] = *(const bf16x8*)&As[row][chunk * 8];
            }
#pragma unroll
            for (int n = 0; n < 4; ++n) {
                int row = wn * 64 + n * 16 + fr;
                int chunk = (ks * 4 + kg) ^ (row & 7);
                bfr[n] = *(const bf16x8*)&Bs[row][chunk * 8];
            }
#pragma unroll
            for (int m = 0; m < 4; ++m)
#pragma unroll
                for (int n = 0; n < 4; ++n)
                    acc[m][n] = __builtin_amdgcn_mfma_f32_16x16x32_bf16(af[m], bfr[n], acc[m][n], 0, 0, 0);
        }
        __syncthreads();   // protect LDS overwrite next iteration
    }

    // epilogue: C/D layout col=lane&15, row=(lane>>4)*4+reg
#pragma unroll
    for (int m = 0; m < 4; ++m) {
        int rbase = m0 + wm * 64 + m * 16 + (lane >> 4) * 4;
#pragma unroll
        for (int n = 0; n < 4; ++n) {
            int col = n0 + wn * 64 + n * 16 + fr;
#pragma unroll
            for (int j = 0; j < 4; ++j)
                C[(size_t)(rbase + j) * ldc + col] = acc[m][n][j];
        }
    }
}

// ---------------- fused LSTM cell elementwise ----------------
// preact = gates[b][g*1024+j] + bias[g*1024+j] (+ x[b,t]*wih1[g*1024+j] for layer 1)
__global__ void k_cell(const float* __restrict__ gates, const float* __restrict__ bias,
                       const float* __restrict__ wih1,   // nullptr for layer 2
                       const float* __restrict__ x, int t,
                       float* __restrict__ c, __hip_bfloat16* __restrict__ hout) {
    int i = blockIdx.x * blockDim.x + threadIdx.x;   // over B*H
    if (i >= B_SZ * H_SZ) return;
    int b = i >> 10, j = i & 1023;
    const float* g = gates + (size_t)b * G4;
    float gi = g[j]        + bias[j];
    float gf = g[1024 + j] + bias[1024 + j];
    float gg = g[2048 + j] + bias[2048 + j];
    float go = g[3072 + j] + bias[3072 + j];
    if (wih1 != nullptr) {
        float xv = x[b * T_SZ + t];
        gi += xv * wih1[j];
        gf += xv * wih1[1024 + j];
        gg += xv * wih1[2048 + j];
        go += xv * wih1[3072 + j];
    }
    float si = 1.f / (1.f + __expf(-gi));
    float sf = 1.f / (1.f + __expf(-gf));
    float so = 1.f / (1.f + __expf(-go));
    float tg = tanhf(gg);
    float cn = sf * c[i] + si * tg;
    c[i] = cn;
    hout[(size_t)b * 2048 + j] = __float2bfloat16(so * tanhf(cn));
}

// ---------------- output projection: out[b,o] = h2[b,:]·Wout[o,:] + bout[o] ----------------
__global__ __launch_bounds__(256)
void k_out(const __hip_bfloat16* __restrict__ A2, const float* __restrict__ Wout,
           const float* __restrict__ bout, float* __restrict__ out) {
    int gw   = (blockIdx.x * blockDim.x + threadIdx.x) >> 6;  // one wave per batch row
    int lane = threadIdx.x & 63;
    if (gw >= B_SZ) return;
    const __hip_bfloat16* h = A2 + (size_t)gw * 2048 + 1024;
    float a0 = 0.f, a1 = 0.f;
#pragma unroll
    for (int k = lane; k < 1024; k += 64) {
        float hv = __bfloat162float(h[k]);
        a0 += hv * Wout[k];
        a1 += hv * Wout[1024 + k];
    }
    for (int off = 32; off; off >>= 1) {
        a0 += __shfl_down(a0, off);
        a1 += __shfl_down(a1, off);
    }
    if (lane == 0) {
        out[gw * 2 + 0] = a0 + bout[0];
        out[gw * 2 + 1] = a1 + bout[1];
    }
}

extern "C" void kernel_launch(void* const* d_in, const int* in_sizes, int n_in,
                              void* d_out, int out_size, void* d_ws, size_t ws_size,
                              hipStream_t stream) {
    const float* x    = (const float*)d_in[0];
    const float* h1_0 = (const float*)d_in[1];
    const float* c1_0 = (const float*)d_in[2];
    const float* h2_0 = (const float*)d_in[3];
    const float* c2_0 = (const float*)d_in[4];
    const float* Wih1 = (const float*)d_in[5];   // [4096,1] -> flat [4096]
    const float* Whh1 = (const float*)d_in[6];
    const float* bih1 = (const float*)d_in[7];
    const float* bhh1 = (const float*)d_in[8];
    const float* Wih2 = (const float*)d_in[9];
    const float* Whh2 = (const float*)d_in[10];
    const float* bih2 = (const float*)d_in[11];
    const float* bhh2 = (const float*)d_in[12];
    const float* Wout = (const float*)d_in[13];
    const float* bout = (const float*)d_in[14];
    float* out = (float*)d_out;
    (void)in_sizes; (void)n_in; (void)out_size; (void)ws_size;

    uint8_t* ws = (uint8_t*)d_ws;
    size_t off = 0;
    auto alloc = [&](size_t bytes) { void* p = ws + off; off += (bytes + 255) & ~(size_t)255; return p; };
    float*          gates = (float*)alloc((size_t)B_SZ * G4 * 4);           // 128 MB
    __hip_bfloat16* A2    = (__hip_bfloat16*)alloc((size_t)B_SZ * 2048 * 2); // 32 MB [h1|h2]
    float*          c1    = (float*)alloc((size_t)B_SZ * H_SZ * 4);          // 32 MB
    float*          c2    = (float*)alloc((size_t)B_SZ * H_SZ * 4);          // 32 MB
    __hip_bfloat16* Whh1b = (__hip_bfloat16*)alloc((size_t)G4 * H_SZ * 2);   // 8 MB
    __hip_bfloat16* Wcat2 = (__hip_bfloat16*)alloc((size_t)G4 * 2048 * 2);   // 16 MB
    float*          bias1 = (float*)alloc(G4 * 4);
    float*          bias2 = (float*)alloc(G4 * 4);

    // ---- prep ----
    k_cvt_bf16<<<(G4 * H_SZ + 255) / 256, 256, 0, stream>>>(Whh1, Whh1b, G4 * H_SZ);
    k_build_wcat<<<(G4 * 2048 + 255) / 256, 256, 0, stream>>>(Wih2, Whh2, Wcat2);
    k_bias<<<(G4 + 255) / 256, 256, 0, stream>>>(bih1, bhh1, bih2, bhh2, bias1, bias2);
    k_init_state<<<(B_SZ * H_SZ + 255) / 256, 256, 0, stream>>>(h1_0, c1_0, h2_0, c2_0, A2, c1, c2);

    dim3 gemm_grid(G4 / BN, B_SZ / BM);   // (32, 64)
    const int cell_blocks = (B_SZ * H_SZ + 255) / 256;

    for (int t = 0; t < T_SZ; ++t) {
        // layer 1: gates = h1_{t-1} @ Whh1^T   (A2 first half, lda=2048)
        k_gemm_bt<<<gemm_grid, 256, 0, stream>>>((const __hip_bfloat16*)A2, 2048, Whh1b, 1024,
                                                 gates, G4, 1024);
        k_cell<<<cell_blocks, 256, 0, stream>>>(gates, bias1, Wih1, x, t, c1, A2);
        // layer 2: gates = [h1_t | h2_{t-1}] @ Wcat^T  (K=2048)
        k_gemm_bt<<<gemm_grid, 256, 0, stream>>>((const __hip_bfloat16*)A2, 2048, Wcat2, 2048,
                                                 gates, G4, 2048);
        k_cell<<<cell_blocks, 256, 0, stream>>>(gates, bias2, nullptr, nullptr, 0, c2, A2 + 1024);
    }
    k_out<<<(B_SZ * 64 + 255) / 256, 256, 0, stream>>>(A2, Wout, bout, out);
}

// Round 2
// 6604.021 us; speedup vs baseline: 1.2335x; 1.2335x over previous
//
#include <hip/hip_runtime.h>
#include <hip/hip_bf16.h>
#include <stdint.h>

#define B_SZ 8192
#define T_SZ 24
#define H_SZ 1024
#define G4   4096   // 4*H

typedef __attribute__((ext_vector_type(8))) short bf16x8;
typedef __attribute__((ext_vector_type(4))) float f32x4;

// Gate-interleaved permutation: new row p -> old row.
// Within each 64-row block: rows 0-15 = gate i (units u0..u0+15), 16-31 = f,
// 32-47 = g, 48-63 = o. So a wave's 64-col tile holds 16 complete units.
__device__ __forceinline__ int perm_old(int p) {
    int gate = (p >> 4) & 3;
    int unit = ((p >> 6) << 4) | (p & 15);
    return gate * 1024 + unit;
}

// ---------------- prep kernels (run once per launch) ----------------
__global__ void k_prep_w1(const float* __restrict__ Whh1, __hip_bfloat16* __restrict__ dst) {
    int i = blockIdx.x * blockDim.x + threadIdx.x;   // over 4096*1024
    int p = i >> 10, k = i & 1023;
    dst[i] = __float2bfloat16(Whh1[(size_t)perm_old(p) * 1024 + k]);
}

__global__ void k_prep_w2(const float* __restrict__ Wih2, const float* __restrict__ Whh2,
                          __hip_bfloat16* __restrict__ dst) {
    int i = blockIdx.x * blockDim.x + threadIdx.x;   // over 4096*2048
    int p = i >> 11, k = i & 2047;
    int old = perm_old(p);
    float v = (k < 1024) ? Wih2[(size_t)old * 1024 + k] : Whh2[(size_t)old * 1024 + (k - 1024)];
    dst[i] = __float2bfloat16(v);
}

__global__ void k_prep_vec(const float* __restrict__ bih1, const float* __restrict__ bhh1,
                           const float* __restrict__ bih2, const float* __restrict__ bhh2,
                           const float* __restrict__ Wih1,
                           float* __restrict__ b1p, float* __restrict__ b2p,
                           float* __restrict__ w1p) {
    int p = blockIdx.x * blockDim.x + threadIdx.x;
    if (p >= G4) return;
    int old = perm_old(p);
    b1p[p] = bih1[old] + bhh1[old];
    b2p[p] = bih2[old] + bhh2[old];
    w1p[p] = Wih1[old];
}

__global__ void k_xT(const float* __restrict__ x, float* __restrict__ xT) {
    int i = blockIdx.x * blockDim.x + threadIdx.x;   // over B*T
    if (i >= B_SZ * T_SZ) return;
    int b = i / T_SZ, t = i % T_SZ;
    xT[t * B_SZ + b] = x[i];
}

// h double-buffer: P_t = A2[t&1], layout [B][2048] = [h1 | h2].
// init: h1_0 -> A2[1] first half (P_{-1}), h2_0 -> A2[0] second half (P_0).
__global__ void k_init_state(const float* __restrict__ h1_0, const float* __restrict__ c1_0,
                             const float* __restrict__ h2_0, const float* __restrict__ c2_0,
                             __hip_bfloat16* __restrict__ A2_0, __hip_bfloat16* __restrict__ A2_1,
                             float* __restrict__ c1, float* __restrict__ c2) {
    int i = blockIdx.x * blockDim.x + threadIdx.x;   // over B*H
    if (i >= B_SZ * H_SZ) return;
    int b = i >> 10, j = i & 1023;
    A2_1[(size_t)b * 2048 + j]        = __float2bfloat16(h1_0[i]);
    A2_0[(size_t)b * 2048 + 1024 + j] = __float2bfloat16(h2_0[i]);
    c1[i] = c1_0[i];
    c2[i] = c2_0[i];
}

// ---------------- fused GEMM + LSTM cell ----------------
// C_gates[M,N] = A[M,K] * Bw[N,K]^T with gate-interleaved N, then the cell
// computed in-register in the epilogue: c updated in place, h written bf16.
// m97 structure: 128x128 tile, BK=64, 4 waves (2x2), 16x16x32 MFMA,
// global_load_lds w=16, XOR-swizzled global source, XCD-aware block swizzle.
#define BM 128
#define BN 128
#define BK 64

template<int LAYER>
__global__ __launch_bounds__(256)
void k_gemm_cell(const __hip_bfloat16* __restrict__ A, int lda,
                 const __hip_bfloat16* __restrict__ Bw, int ldb, int K,
                 const float* __restrict__ biasp, const float* __restrict__ wih1p,
                 const float* __restrict__ xT, int t,
                 float* __restrict__ c, __hip_bfloat16* __restrict__ hout) {
    __shared__ short As[BM][BK];
    __shared__ short Bs[BN][BK];
    const int tid  = threadIdx.x;
    const int lane = tid & 63;
    const int wid  = tid >> 6;

    // XCD-aware swizzle: 2048 blocks, 8 XCDs, 256 contiguous per XCD (bijective)
    const int bid = blockIdx.x;
    const int swz = (bid & 7) * 256 + (bid >> 3);
    const int n0 = (swz & 31) * BN;
    const int m0 = (swz >> 5) * BM;

    const int wm = wid >> 1, wn = wid & 1;
    const int fr = lane & 15;   // fragment row/col
    const int kg = lane >> 4;   // k-group 0..3

    f32x4 acc[4][4];
#pragma unroll
    for (int i = 0; i < 4; ++i)
#pragma unroll
        for (int j = 0; j < 4; ++j) acc[i][j] = (f32x4)0.f;

    for (int kt = 0; kt < K; kt += BK) {
#pragma unroll
        for (int it = 0; it < 4; ++it) {
            int cbase = it * 256 + wid * 64;       // wave-uniform chunk base
            int ci  = cbase + lane;
            int row = ci >> 3, cr = ci & 7;
            int scol = ((cr ^ (row & 7)) << 3);    // pre-swizzled source column
            const __hip_bfloat16* ga = A  + (size_t)(m0 + row) * lda + kt + scol;
            const __hip_bfloat16* gb = Bw + (size_t)(n0 + row) * ldb + kt + scol;
            __builtin_amdgcn_global_load_lds(
                (const __attribute__((address_space(1))) void*)ga,
                (__attribute__((address_space(3))) void*)(&As[0][0] + (size_t)cbase * 8),
                16, 0, 0);
            __builtin_amdgcn_global_load_lds(
                (const __attribute__((address_space(1))) void*)gb,
                (__attribute__((address_space(3))) void*)(&Bs[0][0] + (size_t)cbase * 8),
                16, 0, 0);
        }
        __syncthreads();

#pragma unroll
        for (int ks = 0; ks < 2; ++ks) {
            bf16x8 af[4], bfr[4];
#pragma unroll
            for (int m = 0; m < 4; ++m) {
                int row = wm * 64 + m * 16 + fr;
                int chunk = (ks * 4 + kg) ^ (row & 7);
                af[m] = *(const bf16x8*)&As[row][chunk * 8];
            }
#pragma unroll
            for (int n = 0; n < 4; ++n) {
                int row = wn * 64 + n * 16 + fr;
                int chunk = (ks * 4 + kg) ^ (row & 7);
                bfr[n] = *(const bf16x8*)&Bs[row][chunk * 8];
            }
#pragma unroll
            for (int m = 0; m < 4; ++m)
#pragma unroll
                for (int n = 0; n < 4; ++n)
                    acc[m][n] = __builtin_amdgcn_mfma_f32_16x16x32_bf16(af[m], bfr[n], acc[m][n], 0, 0, 0);
        }
        __syncthreads();
    }

    // ---- fused cell epilogue ----
    // fragment n = gate n (i,f,g,o); lane fr = unit within the wave's 16-unit group
    float biasv[4], xwv[4];
#pragma unroll
    for (int n = 0; n < 4; ++n) {
        int col = n0 + wn * 64 + n * 16 + fr;
        biasv[n] = biasp[col];
        if (LAYER == 1) xwv[n] = wih1p[col];
    }
    const int u = ((n0 >> 6) + wn) * 16 + fr;   // global unit index 0..1023

#pragma unroll
    for (int m = 0; m < 4; ++m) {
        int rbase = m0 + wm * 64 + m * 16 + (lane >> 4) * 4;
#pragma unroll
        for (int j = 0; j < 4; ++j) {
            int b = rbase + j;
            float gi = acc[m][0][j] + biasv[0];
            float gf = acc[m][1][j] + biasv[1];
            float gg = acc[m][2][j] + biasv[2];
            float go = acc[m][3][j] + biasv[3];
            if (LAYER == 1) {
                float xv = xT[t * B_SZ + b];
                gi += xv * xwv[0];
                gf += xv * xwv[1];
                gg += xv * xwv[2];
                go += xv * xwv[3];
            }
            float si = 1.f / (1.f + __expf(-gi));
            float sf = 1.f / (1.f + __expf(-gf));
            float so = 1.f / (1.f + __expf(-go));
            float tg = tanhf(gg);
            size_t ci = (size_t)b * H_SZ + u;
            float cn = sf * c[ci] + si * tg;
            c[ci] = cn;
            hout[(size_t)b * 2048 + u] = __float2bfloat16(so * tanhf(cn));
        }
    }
}

// ---------------- output projection ----------------
__global__ __launch_bounds__(256)
void k_out(const __hip_bfloat16* __restrict__ h2base, const float* __restrict__ Wout,
           const float* __restrict__ bout, float* __restrict__ out) {
    int gw   = (blockIdx.x * blockDim.x + threadIdx.x) >> 6;  // one wave per batch row
    int lane = threadIdx.x & 63;
    if (gw >= B_SZ) return;
    const __hip_bfloat16* h = h2base + (size_t)gw * 2048;
    float a0 = 0.f, a1 = 0.f;
#pragma unroll
    for (int k = lane; k < 1024; k += 64) {
        float hv = __bfloat162float(h[k]);
        a0 += hv * Wout[k];
        a1 += hv * Wout[1024 + k];
    }
    for (int off = 32; off; off >>= 1) {
        a0 += __shfl_down(a0, off);
        a1 += __shfl_down(a1, off);
    }
    if (lane == 0) {
        out[gw * 2 + 0] = a0 + bout[0];
        out[gw * 2 + 1] = a1 + bout[1];
    }
}

extern "C" void kernel_launch(void* const* d_in, const int* in_sizes, int n_in,
                              void* d_out, int out_size, void* d_ws, size_t ws_size,
                              hipStream_t stream) {
    const float* x    = (const float*)d_in[0];
    const float* h1_0 = (const float*)d_in[1];
    const float* c1_0 = (const float*)d_in[2];
    const float* h2_0 = (const float*)d_in[3];
    const float* c2_0 = (const float*)d_in[4];
    const float* Wih1 = (const float*)d_in[5];   // [4096,1] -> flat [4096]
    const float* Whh1 = (const float*)d_in[6];
    const float* bih1 = (const float*)d_in[7];
    const float* bhh1 = (const float*)d_in[8];
    const float* Wih2 = (const float*)d_in[9];
    const float* Whh2 = (const float*)d_in[10];
    const float* bih2 = (const float*)d_in[11];
    const float* bhh2 = (const float*)d_in[12];
    const float* Wout = (const float*)d_in[13];
    const float* bout = (const float*)d_in[14];
    float* out = (float*)d_out;
    (void)in_sizes; (void)n_in; (void)out_size; (void)ws_size;

    uint8_t* ws = (uint8_t*)d_ws;
    size_t off = 0;
    auto alloc = [&](size_t bytes) { void* p = ws + off; off += (bytes + 255) & ~(size_t)255; return p; };
    __hip_bfloat16* A2_0  = (__hip_bfloat16*)alloc((size_t)B_SZ * 2048 * 2);  // 32 MB
    __hip_bfloat16* A2_1  = (__hip_bfloat16*)alloc((size_t)B_SZ * 2048 * 2);  // 32 MB
    float*          c1    = (float*)alloc((size_t)B_SZ * H_SZ * 4);           // 32 MB
    float*          c2    = (float*)alloc((size_t)B_SZ * H_SZ * 4);           // 32 MB
    __hip_bfloat16* Whh1p = (__hip_bfloat16*)alloc((size_t)G4 * H_SZ * 2);    // 8 MB
    __hip_bfloat16* Wcat2p= (__hip_bfloat16*)alloc((size_t)G4 * 2048 * 2);    // 16 MB
    float*          bias1p= (float*)alloc(G4 * 4);
    float*          bias2p= (float*)alloc(G4 * 4);
    float*          wih1p = (float*)alloc(G4 * 4);
    float*          xT    = (float*)alloc((size_t)T_SZ * B_SZ * 4);           // 768 KB

    __hip_bfloat16* A2[2] = { A2_0, A2_1 };

    // ---- prep ----
    k_prep_w1<<<(G4 * H_SZ + 255) / 256, 256, 0, stream>>>(Whh1, Whh1p);
    k_prep_w2<<<(G4 * 2048 + 255) / 256, 256, 0, stream>>>(Wih2, Whh2, Wcat2p);
    k_prep_vec<<<(G4 + 255) / 256, 256, 0, stream>>>(bih1, bhh1, bih2, bhh2, Wih1,
                                                     bias1p, bias2p, wih1p);
    k_xT<<<(B_SZ * T_SZ + 255) / 256, 256, 0, stream>>>(x, xT);
    k_init_state<<<(B_SZ * H_SZ + 255) / 256, 256, 0, stream>>>(h1_0, c1_0, h2_0, c2_0,
                                                                A2_0, A2_1, c1, c2);

    const int gemm_blocks = (B_SZ / BM) * (G4 / BN);   // 2048

    for (int t = 0; t < T_SZ; ++t) {
        __hip_bfloat16* Pprev = A2[(t + 1) & 1];   // P_{t-1}
        __hip_bfloat16* Pt    = A2[t & 1];         // P_t
        // layer 1: reads h1_{t-1} (Pprev first half), writes h1_t -> Pt first half
        k_gemm_cell<1><<<gemm_blocks, 256, 0, stream>>>(
            (const __hip_bfloat16*)Pprev, 2048, Whh1p, 1024, 1024,
            bias1p, wih1p, xT, t, c1, Pt);
        // layer 2: reads [h1_t | h2_{t-1}] = Pt, writes h2_t -> P_{t+1} second half
        k_gemm_cell<2><<<gemm_blocks, 256, 0, stream>>>(
            (const __hip_bfloat16*)Pt, 2048, Wcat2p, 2048, 2048,
            bias2p, nullptr, nullptr, 0, c2, A2[(t + 1) & 1] + 1024);
    }
    // final h2 is in P_24 = A2[0] second half (T=24 even)
    k_out<<<(B_SZ * 64 + 255) / 256, 256, 0, stream>>>(A2_0 + 1024, Wout, bout, out);
}

// Round 3
// 5884.625 us; speedup vs baseline: 1.3843x; 1.1223x over previous
//
#include <hip/hip_runtime.h>
#include <hip/hip_bf16.h>
#include <stdint.h>

#define B_SZ 8192
#define T_SZ 24
#define H_SZ 1024
#define G4   4096   // 4*H

typedef __attribute__((ext_vector_type(8))) short bf16x8;
typedef __attribute__((ext_vector_type(4))) float f32x4;

// Gate-interleaved permutation: new row p -> old row.
// Within each 64-row block: rows 0-15 = gate i (units u0..u0+15), 16-31 = f,
// 32-47 = g, 48-63 = o. So a 64-col wave band holds 16 complete units.
__device__ __forceinline__ int perm_old(int p) {
    int gate = (p >> 4) & 3;
    int unit = ((p >> 6) << 4) | (p & 15);
    return gate * 1024 + unit;
}

// ---------------- prep kernels (run once per launch) ----------------
__global__ void k_prep_w1(const float* __restrict__ Whh1, __hip_bfloat16* __restrict__ dst) {
    int i = blockIdx.x * blockDim.x + threadIdx.x;   // over 4096*1024
    int p = i >> 10, k = i & 1023;
    dst[i] = __float2bfloat16(Whh1[(size_t)perm_old(p) * 1024 + k]);
}

__global__ void k_prep_w2(const float* __restrict__ Wih2, const float* __restrict__ Whh2,
                          __hip_bfloat16* __restrict__ dst) {
    int i = blockIdx.x * blockDim.x + threadIdx.x;   // over 4096*2048
    int p = i >> 11, k = i & 2047;
    int old = perm_old(p);
    float v = (k < 1024) ? Wih2[(size_t)old * 1024 + k] : Whh2[(size_t)old * 1024 + (k - 1024)];
    dst[i] = __float2bfloat16(v);
}

__global__ void k_prep_vec(const float* __restrict__ bih1, const float* __restrict__ bhh1,
                           const float* __restrict__ bih2, const float* __restrict__ bhh2,
                           const float* __restrict__ Wih1,
                           float* __restrict__ b1p, float* __restrict__ b2p,
                           float* __restrict__ w1p) {
    int p = blockIdx.x * blockDim.x + threadIdx.x;
    if (p >= G4) return;
    int old = perm_old(p);
    b1p[p] = bih1[old] + bhh1[old];
    b2p[p] = bih2[old] + bhh2[old];
    w1p[p] = Wih1[old];
}

__global__ void k_xT(const float* __restrict__ x, float* __restrict__ xT) {
    int i = blockIdx.x * blockDim.x + threadIdx.x;   // over B*T
    if (i >= B_SZ * T_SZ) return;
    int b = i / T_SZ, t = i % T_SZ;
    xT[t * B_SZ + b] = x[i];
}

// h double-buffer: P_t = A2[t&1], layout [B][2048] = [h1 | h2].
__global__ void k_init_state(const float* __restrict__ h1_0, const float* __restrict__ c1_0,
                             const float* __restrict__ h2_0, const float* __restrict__ c2_0,
                             __hip_bfloat16* __restrict__ A2_0, __hip_bfloat16* __restrict__ A2_1,
                             float* __restrict__ c1, float* __restrict__ c2) {
    int i = blockIdx.x * blockDim.x + threadIdx.x;   // over B*H
    if (i >= B_SZ * H_SZ) return;
    int b = i >> 10, j = i & 1023;
    A2_1[(size_t)b * 2048 + j]        = __float2bfloat16(h1_0[i]);
    A2_0[(size_t)b * 2048 + 1024 + j] = __float2bfloat16(h2_0[i]);
    c1[i] = c1_0[i];
    c2[i] = c2_0[i];
}

// ---------------- fused GEMM + LSTM cell, 256x256 counted-vmcnt pipeline ----------
// C_gates[M,N] = A[M,K] * Bw[N,K]^T, gate-interleaved N, cell in epilogue.
// 8 waves (2M x 4N), per-wave 128x64 output, BK=64, LDS 2x{A 256x64, B 256x64}
// double-buffered (128 KiB). Counted s_waitcnt vmcnt(8): 2 K-tiles in flight,
// never drained to 0 in the main loop; raw s_barrier (no compiler vmcnt(0)).
// Stage of kt+2 -> buf[kt&1] issued only AFTER the barrier ending kt's compute.
#define BM 256
#define BN 256
#define BK 64

template<int LAYER>
__global__ __launch_bounds__(512, 2)
void k_gemm_cell(const __hip_bfloat16* __restrict__ A, int lda,
                 const __hip_bfloat16* __restrict__ Bw, int ldb, int K,
                 const float* __restrict__ biasp, const float* __restrict__ wih1p,
                 const float* __restrict__ xT, int t,
                 float* __restrict__ c, __hip_bfloat16* __restrict__ hout) {
    __shared__ short As[2][BM][BK];   // 64 KiB
    __shared__ short Bs[2][BN][BK];   // 64 KiB
    const int tid  = threadIdx.x;
    const int lane = tid & 63;
    const int wid  = tid >> 6;        // 0..7

    // XCD-aware swizzle: 512 blocks, 8 XCDs, 64 contiguous per XCD (bijective)
    const int bid = blockIdx.x;
    const int swz = (bid & 7) * 64 + (bid >> 3);
    const int n0 = (swz & 15) * BN;   // N = 4096 -> 16 col-blocks
    const int m0 = (swz >> 4) * BM;   // M = 8192 -> 32 row-blocks

    const int wm = wid >> 2;          // 0..1  (M half)
    const int wn = wid & 3;           // 0..3  (N quarter)
    const int fr = lane & 15;         // fragment row/col
    const int kg = lane >> 4;         // k-group 0..3

    f32x4 acc[8][4];
#pragma unroll
    for (int i = 0; i < 8; ++i)
#pragma unroll
        for (int j = 0; j < 4; ++j) acc[i][j] = (f32x4)0.f;

    // stage one K-tile (A + B) into buffer `buf`: 8 global_load_lds per thread
    auto stage = [&](int kt, int buf) {
#pragma unroll
        for (int it = 0; it < 4; ++it) {
            int cbase = it * 512 + wid * 64;       // wave-uniform chunk base
            int ci  = cbase + lane;
            int row = ci >> 3, cr = ci & 7;
            int scol = ((cr ^ (row & 7)) << 3);    // pre-swizzled source column
            const __hip_bfloat16* ga = A  + (size_t)(m0 + row) * lda + kt * BK + scol;
            const __hip_bfloat16* gb = Bw + (size_t)(n0 + row) * ldb + kt * BK + scol;
            __builtin_amdgcn_global_load_lds(
                (const __attribute__((address_space(1))) void*)ga,
                (__attribute__((address_space(3))) void*)(&As[buf][0][0] + (size_t)cbase * 8),
                16, 0, 0);
            __builtin_amdgcn_global_load_lds(
                (const __attribute__((address_space(1))) void*)gb,
                (__attribute__((address_space(3))) void*)(&Bs[buf][0][0] + (size_t)cbase * 8),
                16, 0, 0);
        }
    };

    const int NK = K >> 6;
    stage(0, 0);
    stage(1, 1);

    for (int kt = 0; kt < NK; ++kt) {
        const int buf = kt & 1;
        if (kt + 1 < NK) asm volatile("s_waitcnt vmcnt(8)" ::: "memory");
        else             asm volatile("s_waitcnt vmcnt(0)" ::: "memory");
        __builtin_amdgcn_s_barrier();      // all waves' loads for kt have landed
        asm volatile("" ::: "memory");

        __builtin_amdgcn_s_setprio(1);
#pragma unroll
        for (int ks = 0; ks < 2; ++ks) {
            bf16x8 bfrag[4];
#pragma unroll
            for (int n = 0; n < 4; ++n) {
                int row = wn * 64 + n * 16 + fr;
                int chunk = (ks * 4 + kg) ^ (row & 7);
                bfrag[n] = *(const bf16x8*)&Bs[buf][row][chunk * 8];
            }
#pragma unroll
            for (int m = 0; m < 8; ++m) {
                int row = wm * 128 + m * 16 + fr;
                int chunk = (ks * 4 + kg) ^ (row & 7);
                bf16x8 afrag = *(const bf16x8*)&As[buf][row][chunk * 8];
#pragma unroll
                for (int n = 0; n < 4; ++n)
                    acc[m][n] = __builtin_amdgcn_mfma_f32_16x16x32_bf16(afrag, bfrag[n], acc[m][n], 0, 0, 0);
            }
        }
        __builtin_amdgcn_s_setprio(0);

        asm volatile("" ::: "memory");
        __builtin_amdgcn_s_barrier();      // all waves done reading buf
        asm volatile("" ::: "memory");
        if (kt + 2 < NK) stage(kt + 2, buf);
    }

    // ---- fused cell epilogue ----
    float biasv[4], xwv[4];
#pragma unroll
    for (int n = 0; n < 4; ++n) {
        int col = n0 + wn * 64 + n * 16 + fr;
        biasv[n] = biasp[col];
        if (LAYER == 1) xwv[n] = wih1p[col];
    }
    const int u = ((n0 >> 6) + wn) * 16 + fr;   // global unit index 0..1023

#pragma unroll
    for (int m = 0; m < 8; ++m) {
        int rbase = m0 + wm * 128 + m * 16 + (lane >> 4) * 4;
#pragma unroll
        for (int j = 0; j < 4; ++j) {
            int b = rbase + j;
            float gi = acc[m][0][j] + biasv[0];
            float gf = acc[m][1][j] + biasv[1];
            float gg = acc[m][2][j] + biasv[2];
            float go = acc[m][3][j] + biasv[3];
            if (LAYER == 1) {
                float xv = xT[t * B_SZ + b];
                gi += xv * xwv[0];
                gf += xv * xwv[1];
                gg += xv * xwv[2];
                go += xv * xwv[3];
            }
            float si = 1.f / (1.f + __expf(-gi));
            float sf = 1.f / (1.f + __expf(-gf));
            float so = 1.f / (1.f + __expf(-go));
            float tg = tanhf(gg);
            size_t ci = (size_t)b * H_SZ + u;
            float cn = sf * c[ci] + si * tg;
            c[ci] = cn;
            hout[(size_t)b * 2048 + u] = __float2bfloat16(so * tanhf(cn));
        }
    }
}

// ---------------- output projection ----------------
__global__ __launch_bounds__(256)
void k_out(const __hip_bfloat16* __restrict__ h2base, const float* __restrict__ Wout,
           const float* __restrict__ bout, float* __restrict__ out) {
    int gw   = (blockIdx.x * blockDim.x + threadIdx.x) >> 6;  // one wave per batch row
    int lane = threadIdx.x & 63;
    if (gw >= B_SZ) return;
    const __hip_bfloat16* h = h2base + (size_t)gw * 2048;
    float a0 = 0.f, a1 = 0.f;
#pragma unroll
    for (int k = lane; k < 1024; k += 64) {
        float hv = __bfloat162float(h[k]);
        a0 += hv * Wout[k];
        a1 += hv * Wout[1024 + k];
    }
    for (int off = 32; off; off >>= 1) {
        a0 += __shfl_down(a0, off);
        a1 += __shfl_down(a1, off);
    }
    if (lane == 0) {
        out[gw * 2 + 0] = a0 + bout[0];
        out[gw * 2 + 1] = a1 + bout[1];
    }
}

extern "C" void kernel_launch(void* const* d_in, const int* in_sizes, int n_in,
                              void* d_out, int out_size, void* d_ws, size_t ws_size,
                              hipStream_t stream) {
    const float* x    = (const float*)d_in[0];
    const float* h1_0 = (const float*)d_in[1];
    const float* c1_0 = (const float*)d_in[2];
    const float* h2_0 = (const float*)d_in[3];
    const float* c2_0 = (const float*)d_in[4];
    const float* Wih1 = (const float*)d_in[5];   // [4096,1] -> flat [4096]
    const float* Whh1 = (const float*)d_in[6];
    const float* bih1 = (const float*)d_in[7];
    const float* bhh1 = (const float*)d_in[8];
    const float* Wih2 = (const float*)d_in[9];
    const float* Whh2 = (const float*)d_in[10];
    const float* bih2 = (const float*)d_in[11];
    const float* bhh2 = (const float*)d_in[12];
    const float* Wout = (const float*)d_in[13];
    const float* bout = (const float*)d_in[14];
    float* out = (float*)d_out;
    (void)in_sizes; (void)n_in; (void)out_size; (void)ws_size;

    uint8_t* ws = (uint8_t*)d_ws;
    size_t off = 0;
    auto alloc = [&](size_t bytes) { void* p = ws + off; off += (bytes + 255) & ~(size_t)255; return p; };
    __hip_bfloat16* A2_0  = (__hip_bfloat16*)alloc((size_t)B_SZ * 2048 * 2);  // 32 MB
    __hip_bfloat16* A2_1  = (__hip_bfloat16*)alloc((size_t)B_SZ * 2048 * 2);  // 32 MB
    float*          c1    = (float*)alloc((size_t)B_SZ * H_SZ * 4);           // 32 MB
    float*          c2    = (float*)alloc((size_t)B_SZ * H_SZ * 4);           // 32 MB
    __hip_bfloat16* Whh1p = (__hip_bfloat16*)alloc((size_t)G4 * H_SZ * 2);    // 8 MB
    __hip_bfloat16* Wcat2p= (__hip_bfloat16*)alloc((size_t)G4 * 2048 * 2);    // 16 MB
    float*          bias1p= (float*)alloc(G4 * 4);
    float*          bias2p= (float*)alloc(G4 * 4);
    float*          wih1p = (float*)alloc(G4 * 4);
    float*          xT    = (float*)alloc((size_t)T_SZ * B_SZ * 4);           // 768 KB

    __hip_bfloat16* A2[2] = { A2_0, A2_1 };

    // ---- prep ----
    k_prep_w1<<<(G4 * H_SZ + 255) / 256, 256, 0, stream>>>(Whh1, Whh1p);
    k_prep_w2<<<(G4 * 2048 + 255) / 256, 256, 0, stream>>>(Wih2, Whh2, Wcat2p);
    k_prep_vec<<<(G4 + 255) / 256, 256, 0, stream>>>(bih1, bhh1, bih2, bhh2, Wih1,
                                                     bias1p, bias2p, wih1p);
    k_xT<<<(B_SZ * T_SZ + 255) / 256, 256, 0, stream>>>(x, xT);
    k_init_state<<<(B_SZ * H_SZ + 255) / 256, 256, 0, stream>>>(h1_0, c1_0, h2_0, c2_0,
                                                                A2_0, A2_1, c1, c2);

    const int gemm_blocks = (B_SZ / BM) * (G4 / BN);   // 32 * 16 = 512

    for (int t = 0; t < T_SZ; ++t) {
        __hip_bfloat16* Pprev = A2[(t + 1) & 1];   // P_{t-1}
        __hip_bfloat16* Pt    = A2[t & 1];         // P_t
        // layer 1: reads h1_{t-1} (Pprev first half), writes h1_t -> Pt first half
        k_gemm_cell<1><<<gemm_blocks, 512, 0, stream>>>(
            (const __hip_bfloat16*)Pprev, 2048, Whh1p, 1024, 1024,
            bias1p, wih1p, xT, t, c1, Pt);
        // layer 2: reads [h1_t | h2_{t-1}] = Pt, writes h2_t -> P_{t+1} second half
        k_gemm_cell<2><<<gemm_blocks, 512, 0, stream>>>(
            (const __hip_bfloat16*)Pt, 2048, Wcat2p, 2048, 2048,
            bias2p, nullptr, nullptr, 0, c2, A2[(t + 1) & 1] + 1024);
    }
    // final h2 is in P_24 = A2[0] second half (T=24 even)
    k_out<<<(B_SZ * 64 + 255) / 256, 256, 0, stream>>>(A2_0 + 1024, Wout, bout, out);
}

// Round 4
// 5534.979 us; speedup vs baseline: 1.4717x; 1.0632x over previous
//
#include <hip/hip_runtime.h>
#include <hip/hip_bf16.h>
#include <stdint.h>

#define B_SZ 8192
#define T_SZ 24
#define H_SZ 1024
#define G4   4096   // 4*H

typedef __attribute__((ext_vector_type(8))) short bf16x8;
typedef __attribute__((ext_vector_type(4))) float f32x4;

// Gate-interleaved permutation: new row p -> old row.
__device__ __forceinline__ int perm_old(int p) {
    int gate = (p >> 4) & 3;
    int unit = ((p >> 6) << 4) | (p & 15);
    return gate * 1024 + unit;
}

// ---------------- prep kernels (run once per launch) ----------------
__global__ void k_prep_w1(const float* __restrict__ Whh1, __hip_bfloat16* __restrict__ dst) {
    int i = blockIdx.x * blockDim.x + threadIdx.x;   // over 4096*1024
    int p = i >> 10, k = i & 1023;
    dst[i] = __float2bfloat16(Whh1[(size_t)perm_old(p) * 1024 + k]);
}

__global__ void k_prep_w2(const float* __restrict__ Wih2, const float* __restrict__ Whh2,
                          __hip_bfloat16* __restrict__ dst) {
    int i = blockIdx.x * blockDim.x + threadIdx.x;   // over 4096*2048
    int p = i >> 11, k = i & 2047;
    int old = perm_old(p);
    float v = (k < 1024) ? Wih2[(size_t)old * 1024 + k] : Whh2[(size_t)old * 1024 + (k - 1024)];
    dst[i] = __float2bfloat16(v);
}

__global__ void k_prep_vec(const float* __restrict__ bih1, const float* __restrict__ bhh1,
                           const float* __restrict__ bih2, const float* __restrict__ bhh2,
                           const float* __restrict__ Wih1,
                           float* __restrict__ b1p, float* __restrict__ b2p,
                           float* __restrict__ w1p) {
    int p = blockIdx.x * blockDim.x + threadIdx.x;
    if (p >= G4) return;
    int old = perm_old(p);
    b1p[p] = bih1[old] + bhh1[old];
    b2p[p] = bih2[old] + bhh2[old];
    w1p[p] = Wih1[old];
}

__global__ void k_xT(const float* __restrict__ x, float* __restrict__ xT) {
    int i = blockIdx.x * blockDim.x + threadIdx.x;   // over B*T
    if (i >= B_SZ * T_SZ) return;
    int b = i / T_SZ, t = i % T_SZ;
    xT[t * B_SZ + b] = x[i];
}

__global__ void k_init_state(const float* __restrict__ h1_0, const float* __restrict__ c1_0,
                             const float* __restrict__ h2_0, const float* __restrict__ c2_0,
                             __hip_bfloat16* __restrict__ A2_0, __hip_bfloat16* __restrict__ A2_1,
                             float* __restrict__ c1, float* __restrict__ c2) {
    int i = blockIdx.x * blockDim.x + threadIdx.x;   // over B*H
    if (i >= B_SZ * H_SZ) return;
    int b = i >> 10, j = i & 1023;
    A2_1[(size_t)b * 2048 + j]        = __float2bfloat16(h1_0[i]);
    A2_0[(size_t)b * 2048 + 1024 + j] = __float2bfloat16(h2_0[i]);
    c1[i] = c1_0[i];
    c2[i] = c2_0[i];
}

// ---------------- fused GEMM + LSTM cell, 256x256, 4-phase/K-tile pipeline -------
// 8 waves (2M x 4N), per-wave 128x64 C, BK=64. Per K-tile: 4 quadrant phases,
// each {ds_read subtile || issue 1 stage unit -> barrier -> lgkmcnt(0) ->
// setprio(1) -> 16 MFMA -> setprio(0) -> [vmcnt] -> barrier}.
// Stage units (quarter tiles, 2 x global_load_lds/thread each):
//   u1 = A rows (r%128)<64, u2 = A rows (r%128)>=64,
//   u3 = B rows (r%64)<32,  u4 = B rows (r%64)>=32.
// Reads per tile kt (frag-cached in regs, 24 ds_read_b128/wave):
//   p1: A-mq0 + B-nq0, p2: B-nq1, p3: A-mq1, p4: none.
// Issues: p1: u2[kt+1] (other buf), p2: u4[kt+1] (other buf),
//         p3: u1[kt+2] (this buf, region freed after p1),
//         p4: u3[kt+2] (this buf, region freed after p1).
// Waits (before end barrier => all-waves guarantee for next phase's reads):
//   p1-end: vmcnt(6) covers u4[kt] (and u2[kt]) for p2/p3,
//   p4-end: vmcnt(8) covers u1/u3[kt+1] for next p1.
//   Tail: kt==NK-1 p1-end -> vmcnt(0); kt==NK-2 p4-end -> vmcnt(4).
#define BM 256
#define BN 256
#define BK 64

template<int LAYER>
__global__ __launch_bounds__(512, 2)
void k_gemm_cell(const __hip_bfloat16* __restrict__ A, int lda,
                 const __hip_bfloat16* __restrict__ Bw, int ldb, int K,
                 const float* __restrict__ biasp, const float* __restrict__ wih1p,
                 const float* __restrict__ xT, int t,
                 float* __restrict__ c, __hip_bfloat16* __restrict__ hout) {
    __shared__ short As[2][BM][BK];   // 64 KiB
    __shared__ short Bs[2][BN][BK];   // 64 KiB
    const int tid  = threadIdx.x;
    const int lane = tid & 63;
    const int wid  = tid >> 6;        // 0..7

    // XCD-aware swizzle: 512 blocks, 8 XCDs, 64 contiguous per XCD (bijective)
    const int bid = blockIdx.x;
    const int swz = (bid & 7) * 64 + (bid >> 3);
    const int n0 = (swz & 15) * BN;
    const int m0 = (swz >> 4) * BM;

    const int wm = wid >> 2;          // 0..1
    const int wn = wid & 3;           // 0..3
    const int fr = lane & 15;
    const int kg = lane >> 4;

    const __hip_bfloat16* Abase = A  + (size_t)m0 * lda;
    const __hip_bfloat16* Bbase = Bw + (size_t)n0 * ldb;

    f32x4 acc[8][4];
#pragma unroll
    for (int i = 0; i < 8; ++i)
#pragma unroll
        for (int j = 0; j < 4; ++j) acc[i][j] = (f32x4)0.f;

    // one global_load_lds covering 8 LDS rows (lr0 wave-uniform, multiple of 8);
    // source column pre-swizzled (chunk ^= row&7) so linear LDS dest + swizzled
    // read = both-sides involution (rule #21), bank-conflict-free.
    auto stage8A = [&](int buf, int lr0, int kcol) {
        int lr = lr0 + (lane >> 3);
        int cr = lane & 7;
        int scol = ((cr ^ (lr & 7)) << 3);
        const __hip_bfloat16* gp = Abase + (size_t)lr * lda + kcol + scol;
        __builtin_amdgcn_global_load_lds(
            (const __attribute__((address_space(1))) void*)gp,
            (__attribute__((address_space(3))) void*)(&As[buf][lr0][0]), 16, 0, 0);
    };
    auto stage8B = [&](int buf, int lr0, int kcol) {
        int lr = lr0 + (lane >> 3);
        int cr = lane & 7;
        int scol = ((cr ^ (lr & 7)) << 3);
        const __hip_bfloat16* gp = Bbase + (size_t)lr * ldb + kcol + scol;
        __builtin_amdgcn_global_load_lds(
            (const __attribute__((address_space(1))) void*)gp,
            (__attribute__((address_space(3))) void*)(&Bs[buf][lr0][0]), 16, 0, 0);
    };
    auto stage_u1 = [&](int kt, int buf) {   // A rows (r%128)<64
#pragma unroll
        for (int j = 0; j < 2; ++j) {
            int rr0 = (wid * 2 + j) * 8;
            int lr0 = (rr0 < 64) ? rr0 : rr0 + 64;
            stage8A(buf, lr0, kt * BK);
        }
    };
    auto stage_u2 = [&](int kt, int buf) {   // A rows (r%128)>=64
#pragma unroll
        for (int j = 0; j < 2; ++j) {
            int rr0 = (wid * 2 + j) * 8;
            int lr0 = (rr0 < 64) ? rr0 + 64 : rr0 + 128;
            stage8A(buf, lr0, kt * BK);
        }
    };
    auto stage_u3 = [&](int kt, int buf) {   // B rows (r%64)<32
#pragma unroll
        for (int j = 0; j < 2; ++j) {
            int rr0 = (wid * 2 + j) * 8;
            int lr0 = ((rr0 >> 5) << 6) + (rr0 & 31);
            stage8B(buf, lr0, kt * BK);
        }
    };
    auto stage_u4 = [&](int kt, int buf) {   // B rows (r%64)>=32
#pragma unroll
        for (int j = 0; j < 2; ++j) {
            int rr0 = (wid * 2 + j) * 8;
            int lr0 = ((rr0 >> 5) << 6) + 32 + (rr0 & 31);
            stage8B(buf, lr0, kt * BK);
        }
    };

    auto rdA = [&](int buf, int m, int ks) -> bf16x8 {
        int row = wm * 128 + m * 16 + fr;
        int chunk = (ks * 4 + kg) ^ (row & 7);
        return *(const bf16x8*)&As[buf][row][chunk * 8];
    };
    auto rdB = [&](int buf, int n, int ks) -> bf16x8 {
        int row = wn * 64 + n * 16 + fr;
        int chunk = (ks * 4 + kg) ^ (row & 7);
        return *(const bf16x8*)&Bs[buf][row][chunk * 8];
    };

    const int NK = K >> 6;

    // ---- prologue: u1[0] u3[0] u2[0] u4[0] u1[1] u3[1]  (6 units = 12 loads) ----
    stage_u1(0, 0); stage_u3(0, 0); stage_u2(0, 0); stage_u4(0, 0);
    stage_u1(1, 1); stage_u3(1, 1);
    asm volatile("s_waitcnt vmcnt(8)" ::: "memory");   // u1[0],u3[0] landed
    __builtin_amdgcn_s_barrier();

    bf16x8 a0[4][2], a1[4][2], b0[2][2], b1[2][2];

    for (int kt = 0; kt < NK; ++kt) {
        const int buf = kt & 1;

        // ---------- phase 1: quadrant (mq0, nq0) ----------
#pragma unroll
        for (int m = 0; m < 4; ++m)
#pragma unroll
            for (int ks = 0; ks < 2; ++ks) a0[m][ks] = rdA(buf, m, ks);
#pragma unroll
        for (int n = 0; n < 2; ++n)
#pragma unroll
            for (int ks = 0; ks < 2; ++ks) b0[n][ks] = rdB(buf, n, ks);
        if (kt + 1 < NK) stage_u2(kt + 1, buf ^ 1);
        asm volatile("" ::: "memory");
        __builtin_amdgcn_s_barrier();
        asm volatile("s_waitcnt lgkmcnt(0)" ::: "memory");
        __builtin_amdgcn_sched_barrier(0);
        __builtin_amdgcn_s_setprio(1);
#pragma unroll
        for (int ks = 0; ks < 2; ++ks)
#pragma unroll
            for (int m = 0; m < 4; ++m)
#pragma unroll
                for (int n = 0; n < 2; ++n)
                    acc[m][n] = __builtin_amdgcn_mfma_f32_16x16x32_bf16(a0[m][ks], b0[n][ks], acc[m][n], 0, 0, 0);
        __builtin_amdgcn_s_setprio(0);
        if (kt + 1 < NK) asm volatile("s_waitcnt vmcnt(6)" ::: "memory");
        else             asm volatile("s_waitcnt vmcnt(0)" ::: "memory");
        __builtin_amdgcn_s_barrier();

        // ---------- phase 2: quadrant (mq0, nq1) ----------
#pragma unroll
        for (int n = 0; n < 2; ++n)
#pragma unroll
            for (int ks = 0; ks < 2; ++ks) b1[n][ks] = rdB(buf, 2 + n, ks);
        if (kt + 1 < NK) stage_u4(kt + 1, buf ^ 1);
        asm volatile("" ::: "memory");
        __builtin_amdgcn_s_barrier();
        asm volatile("s_waitcnt lgkmcnt(0)" ::: "memory");
        __builtin_amdgcn_sched_barrier(0);
        __builtin_amdgcn_s_setprio(1);
#pragma unroll
        for (int ks = 0; ks < 2; ++ks)
#pragma unroll
            for (int m = 0; m < 4; ++m)
#pragma unroll
                for (int n = 0; n < 2; ++n)
                    acc[m][2 + n] = __builtin_amdgcn_mfma_f32_16x16x32_bf16(a0[m][ks], b1[n][ks], acc[m][2 + n], 0, 0, 0);
        __builtin_amdgcn_s_setprio(0);
        asm volatile("" ::: "memory");
        __builtin_amdgcn_s_barrier();

        // ---------- phase 3: quadrant (mq1, nq0) ----------
#pragma unroll
        for (int m = 0; m < 4; ++m)
#pragma unroll
            for (int ks = 0; ks < 2; ++ks) a1[m][ks] = rdA(buf, 4 + m, ks);
        if (kt + 2 < NK) stage_u1(kt + 2, buf);
        asm volatile("" ::: "memory");
        __builtin_amdgcn_s_barrier();
        asm volatile("s_waitcnt lgkmcnt(0)" ::: "memory");
        __builtin_amdgcn_sched_barrier(0);
        __builtin_amdgcn_s_setprio(1);
#pragma unroll
        for (int ks = 0; ks < 2; ++ks)
#pragma unroll
            for (int m = 0; m < 4; ++m)
#pragma unroll
                for (int n = 0; n < 2; ++n)
                    acc[4 + m][n] = __builtin_amdgcn_mfma_f32_16x16x32_bf16(a1[m][ks], b0[n][ks], acc[4 + m][n], 0, 0, 0);
        __builtin_amdgcn_s_setprio(0);
        asm volatile("" ::: "memory");
        __builtin_amdgcn_s_barrier();

        // ---------- phase 4: quadrant (mq1, nq1) ----------
        if (kt + 2 < NK) stage_u3(kt + 2, buf);
        asm volatile("" ::: "memory");
        __builtin_amdgcn_s_barrier();
        __builtin_amdgcn_s_setprio(1);
#pragma unroll
        for (int ks = 0; ks < 2; ++ks)
#pragma unroll
            for (int m = 0; m < 4; ++m)
#pragma unroll
                for (int n = 0; n < 2; ++n)
                    acc[4 + m][2 + n] = __builtin_amdgcn_mfma_f32_16x16x32_bf16(a1[m][ks], b1[n][ks], acc[4 + m][2 + n], 0, 0, 0);
        __builtin_amdgcn_s_setprio(0);
        if (kt + 2 < NK)      asm volatile("s_waitcnt vmcnt(8)" ::: "memory");
        else if (kt + 1 < NK) asm volatile("s_waitcnt vmcnt(4)" ::: "memory");
        __builtin_amdgcn_s_barrier();
    }

    // ---- fused cell epilogue ----
    float biasv[4], xwv[4];
#pragma unroll
    for (int n = 0; n < 4; ++n) {
        int col = n0 + wn * 64 + n * 16 + fr;
        biasv[n] = biasp[col];
        if (LAYER == 1) xwv[n] = wih1p[col];
    }
    const int u = ((n0 >> 6) + wn) * 16 + fr;   // global unit index 0..1023

#pragma unroll
    for (int m = 0; m < 8; ++m) {
        int rbase = m0 + wm * 128 + m * 16 + (lane >> 4) * 4;
#pragma unroll
        for (int j = 0; j < 4; ++j) {
            int b = rbase + j;
            float gi = acc[m][0][j] + biasv[0];
            float gf = acc[m][1][j] + biasv[1];
            float gg = acc[m][2][j] + biasv[2];
            float go = acc[m][3][j] + biasv[3];
            if (LAYER == 1) {
                float xv = xT[t * B_SZ + b];
                gi += xv * xwv[0];
                gf += xv * xwv[1];
                gg += xv * xwv[2];
                go += xv * xwv[3];
            }
            float si = 1.f / (1.f + __expf(-gi));
            float sf = 1.f / (1.f + __expf(-gf));
            float so = 1.f / (1.f + __expf(-go));
            float tg = tanhf(gg);
            size_t ci = (size_t)b * H_SZ + u;
            float cn = sf * c[ci] + si * tg;
            c[ci] = cn;
            hout[(size_t)b * 2048 + u] = __float2bfloat16(so * tanhf(cn));
        }
    }
}

// ---------------- output projection ----------------
__global__ __launch_bounds__(256)
void k_out(const __hip_bfloat16* __restrict__ h2base, const float* __restrict__ Wout,
           const float* __restrict__ bout, float* __restrict__ out) {
    int gw   = (blockIdx.x * blockDim.x + threadIdx.x) >> 6;
    int lane = threadIdx.x & 63;
    if (gw >= B_SZ) return;
    const __hip_bfloat16* h = h2base + (size_t)gw * 2048;
    float a0 = 0.f, a1 = 0.f;
#pragma unroll
    for (int k = lane; k < 1024; k += 64) {
        float hv = __bfloat162float(h[k]);
        a0 += hv * Wout[k];
        a1 += hv * Wout[1024 + k];
    }
    for (int off = 32; off; off >>= 1) {
        a0 += __shfl_down(a0, off);
        a1 += __shfl_down(a1, off);
    }
    if (lane == 0) {
        out[gw * 2 + 0] = a0 + bout[0];
        out[gw * 2 + 1] = a1 + bout[1];
    }
}

extern "C" void kernel_launch(void* const* d_in, const int* in_sizes, int n_in,
                              void* d_out, int out_size, void* d_ws, size_t ws_size,
                              hipStream_t stream) {
    const float* x    = (const float*)d_in[0];
    const float* h1_0 = (const float*)d_in[1];
    const float* c1_0 = (const float*)d_in[2];
    const float* h2_0 = (const float*)d_in[3];
    const float* c2_0 = (const float*)d_in[4];
    const float* Wih1 = (const float*)d_in[5];
    const float* Whh1 = (const float*)d_in[6];
    const float* bih1 = (const float*)d_in[7];
    const float* bhh1 = (const float*)d_in[8];
    const float* Wih2 = (const float*)d_in[9];
    const float* Whh2 = (const float*)d_in[10];
    const float* bih2 = (const float*)d_in[11];
    const float* bhh2 = (const float*)d_in[12];
    const float* Wout = (const float*)d_in[13];
    const float* bout = (const float*)d_in[14];
    float* out = (float*)d_out;
    (void)in_sizes; (void)n_in; (void)out_size; (void)ws_size;

    uint8_t* ws = (uint8_t*)d_ws;
    size_t off = 0;
    auto alloc = [&](size_t bytes) { void* p = ws + off; off += (bytes + 255) & ~(size_t)255; return p; };
    __hip_bfloat16* A2_0  = (__hip_bfloat16*)alloc((size_t)B_SZ * 2048 * 2);
    __hip_bfloat16* A2_1  = (__hip_bfloat16*)alloc((size_t)B_SZ * 2048 * 2);
    float*          c1    = (float*)alloc((size_t)B_SZ * H_SZ * 4);
    float*          c2    = (float*)alloc((size_t)B_SZ * H_SZ * 4);
    __hip_bfloat16* Whh1p = (__hip_bfloat16*)alloc((size_t)G4 * H_SZ * 2);
    __hip_bfloat16* Wcat2p= (__hip_bfloat16*)alloc((size_t)G4 * 2048 * 2);
    float*          bias1p= (float*)alloc(G4 * 4);
    float*          bias2p= (float*)alloc(G4 * 4);
    float*          wih1p = (float*)alloc(G4 * 4);
    float*          xT    = (float*)alloc((size_t)T_SZ * B_SZ * 4);

    __hip_bfloat16* A2[2] = { A2_0, A2_1 };

    k_prep_w1<<<(G4 * H_SZ + 255) / 256, 256, 0, stream>>>(Whh1, Whh1p);
    k_prep_w2<<<(G4 * 2048 + 255) / 256, 256, 0, stream>>>(Wih2, Whh2, Wcat2p);
    k_prep_vec<<<(G4 + 255) / 256, 256, 0, stream>>>(bih1, bhh1, bih2, bhh2, Wih1,
                                                     bias1p, bias2p, wih1p);
    k_xT<<<(B_SZ * T_SZ + 255) / 256, 256, 0, stream>>>(x, xT);
    k_init_state<<<(B_SZ * H_SZ + 255) / 256, 256, 0, stream>>>(h1_0, c1_0, h2_0, c2_0,
                                                                A2_0, A2_1, c1, c2);

    const int gemm_blocks = (B_SZ / BM) * (G4 / BN);   // 512

    for (int t = 0; t < T_SZ; ++t) {
        __hip_bfloat16* Pprev = A2[(t + 1) & 1];
        __hip_bfloat16* Pt    = A2[t & 1];
        k_gemm_cell<1><<<gemm_blocks, 512, 0, stream>>>(
            (const __hip_bfloat16*)Pprev, 2048, Whh1p, 1024, 1024,
            bias1p, wih1p, xT, t, c1, Pt);
        k_gemm_cell<2><<<gemm_blocks, 512, 0, stream>>>(
            (const __hip_bfloat16*)Pt, 2048, Wcat2p, 2048, 2048,
            bias2p, nullptr, nullptr, 0, c2, A2[(t + 1) & 1] + 1024);
    }
    k_out<<<(B_SZ * 64 + 255) / 256, 256, 0, stream>>>(A2_0 + 1024, Wout, bout, out);
}